// Round 1
// baseline (283.194 us; speedup 1.0000x reference)
//
#include <hip/hip_runtime.h>
#include <hip/hip_fp16.h>
#include <hip/hip_fp8.h>
#include <math.h>

#define NN 40000      // nodes
#define NE 640000     // raw edges
#define ET 680000     // edges + self loops
#define CH 128
#define OC 16
#define NG 64
#define NQ (ET/4)     // 170000 edge quads
#define CAP 48        // padded-CSR capacity per node (deg ~ Poisson(17))
#define NBKT 8        // XCD buckets for pad_fill
#define BKT_DIV 5000  // nodes per bucket
#define NFILLB 5320   // 665 chunks * 8 buckets
#define NGEMMB 625    // 64-row tiles (full 128 cols internal)
#define NGRP 79
#define GRP 72
#define NBLK1 (NGRP*GRP + (NFILLB - NGRP*64))   // 5952

typedef _Float16 h8 __attribute__((ext_vector_type(8)));
typedef float    f4 __attribute__((ext_vector_type(4)));
typedef int      i4 __attribute__((ext_vector_type(4)));

__device__ __forceinline__ float2 fp8x2_to_f32(unsigned short v) {
    __hip_fp8_e4m3 a, b;
    a.__x = (__hip_fp8_storage_t)(v & 0xff);
    b.__x = (__hip_fp8_storage_t)(v >> 8);
    return make_float2((float)a, (float)b);
}
__device__ __forceinline__ unsigned char f32_to_fp8(float f) {
    __hip_fp8_e4m3 t(f);
    return (unsigned char)t.__x;
}

// ---- prep: zero scratch + graph bounds + W->fp16 transposed ---------------
__global__ __launch_bounds__(256)
void prep(const int* __restrict__ batch, int* __restrict__ gstart,
          int* __restrict__ cur_d, int* __restrict__ cur_s,
          float* __restrict__ pooled,
          const float* __restrict__ W1, const float* __restrict__ W2,
          const float* __restrict__ Wg, _Float16* __restrict__ Wt1,
          _Float16* __restrict__ Wt2, _Float16* __restrict__ Wtg)
{
    int i = blockIdx.x * 256 + threadIdx.x;
    if (i < NN) {
        cur_d[i] = 0; cur_s[i] = 0;
        int b = batch[i];
        if (i == 0) { for (int g = 0; g <= b; ++g) gstart[g] = 0; }
        else { int pb = batch[i - 1]; for (int g = pb + 1; g <= b; ++g) gstart[g] = i; }
        if (i == NN - 1) { for (int g = b + 1; g <= NG; ++g) gstart[g] = NN; }
    }
    if (i < NG * CH) pooled[i] = 0.f;
    if (i < CH * CH) {
        int k = i >> 7, n = i & 127;          // coalesced read W[k][n]
        Wt1[n * CH + k] = (_Float16)W1[i];
        Wt2[n * CH + k] = (_Float16)W2[i];
        Wtg[n * CH + k] = (_Float16)Wg[i];
    }
}

// ---- stage Wt (global, [n][k] row-major) into LDS wt[128][136] ------------
__device__ __forceinline__
void stage_w(_Float16 (*wt)[136], const _Float16* __restrict__ Wt, int tid)
{
#pragma unroll
    for (int i = 0; i < 8; ++i) {
        int f = tid + i * 256;            // 0..2047 half8 chunks
        int n = f >> 4, c8 = f & 15;
        *(float4*)&wt[n][c8 * 8] = *(const float4*)(Wt + (size_t)n * CH + c8 * 8);
    }
}

// ---- MFMA body: 64 rows x 128 cols, K=128; xs and wt staged in LDS --------
// A-frag A[m][k=quad*8+j]; C/D col=lane&15, row=quad*4+reg (verified R6).
// b128 LDS reads process 16 lanes/phase -> (m,quad) mapping is 2-way/phase,
// conflict-free. Full row per block -> s[row] is a plain store (no atomic).
template<bool BIAS, bool ATTN>
__device__ __forceinline__
void mfma_body(_Float16 (*xs)[136], _Float16 (*wt)[136],
               const float* __restrict__ bias, const float* __restrict__ att,
               unsigned char* __restrict__ out8, float* __restrict__ s,
               int rb, int tid)
{
    const int wv = tid >> 6, lane = tid & 63;
    const int m = lane & 15, quad = lane >> 4;
    f4 acc[8] = {};
#pragma unroll
    for (int ks = 0; ks < 4; ++ks) {
        h8 a = *(const h8*)&xs[wv * 16 + m][ks * 32 + quad * 8];
#pragma unroll
        for (int t = 0; t < 8; ++t) {
            h8 b = *(const h8*)&wt[t * 16 + m][ks * 32 + quad * 8];
            acc[t] = __builtin_amdgcn_mfma_f32_16x16x32_f16(a, b, acc[t], 0, 0, 0);
        }
    }
    float pr[4] = {0.f, 0.f, 0.f, 0.f};
#pragma unroll
    for (int t = 0; t < 8; ++t) {
        int col = t * 16 + m;
        float bv = BIAS ? bias[col] : 0.f;
        float av = ATTN ? att[col] : 0.f;
#pragma unroll
        for (int r = 0; r < 4; ++r) {
            float o = acc[t][r] + bv;
            int row = rb + wv * 16 + quad * 4 + r;
            out8[(size_t)row * CH + col] = f32_to_fp8(o);
            if (ATTN) pr[r] += o * av;
        }
    }
    if (ATTN) {
#pragma unroll
        for (int r = 0; r < 4; ++r) {
            float p = pr[r];
            p += __shfl_xor(p, 1); p += __shfl_xor(p, 2);
            p += __shfl_xor(p, 4); p += __shfl_xor(p, 8);
            if (m == 0) s[rb + wv * 16 + quad * 4 + r] = p;  // full row here
        }
    }
}

// ---- LDS-free MFMA gemm: A direct from fp32 x (NT load + in-reg cvt), -----
// B direct from L2-resident Wt (32 KB, shared by all blocks). No barrier,
// zero static LDS -> fill blocks co-resident at ~6 blocks/CU instead of 3.
// A-frag row = rb + wv*16 + m; each x element read exactly once per block
// (32B/lane, 128B segments per row) so HBM traffic is identical to staging.
template<bool BIAS, bool ATTN>
__device__ __forceinline__
void gemm_direct(const float* __restrict__ x, const _Float16* __restrict__ Wt,
                 const float* __restrict__ bias, const float* __restrict__ att,
                 unsigned char* __restrict__ out8, float* __restrict__ s,
                 int rb, int tid)
{
    const int wv = tid >> 6, lane = tid & 63;
    const int m = lane & 15, quad = lane >> 4;
    const int arow = rb + wv * 16 + m;
    const float* xp = x + (size_t)arow * CH + quad * 8;
    const _Float16* wbase = Wt + m * CH + quad * 8;
    f4 acc[8] = {};
#pragma unroll
    for (int ks = 0; ks < 4; ++ks) {
        f4 v0 = __builtin_nontemporal_load((const f4*)(xp + ks * 32));
        f4 v1 = __builtin_nontemporal_load((const f4*)(xp + ks * 32) + 1);
        h8 a;
        a[0] = (_Float16)v0[0]; a[1] = (_Float16)v0[1];
        a[2] = (_Float16)v0[2]; a[3] = (_Float16)v0[3];
        a[4] = (_Float16)v1[0]; a[5] = (_Float16)v1[1];
        a[6] = (_Float16)v1[2]; a[7] = (_Float16)v1[3];
#pragma unroll
        for (int t = 0; t < 8; ++t) {
            h8 b = *(const h8*)(wbase + t * 16 * CH + ks * 32);
            acc[t] = __builtin_amdgcn_mfma_f32_16x16x32_f16(a, b, acc[t], 0, 0, 0);
        }
    }
    float pr[4] = {0.f, 0.f, 0.f, 0.f};
#pragma unroll
    for (int t = 0; t < 8; ++t) {
        int col = t * 16 + m;
        float bv = BIAS ? bias[col] : 0.f;
        float av = ATTN ? att[col] : 0.f;
#pragma unroll
        for (int r = 0; r < 4; ++r) {
            float o = acc[t][r] + bv;
            int row = rb + wv * 16 + quad * 4 + r;
            out8[(size_t)row * CH + col] = f32_to_fp8(o);
            if (ATTN) pr[r] += o * av;
        }
    }
    if (ATTN) {
#pragma unroll
        for (int r = 0; r < 4; ++r) {
            float p = pr[r];
            p += __shfl_xor(p, 1); p += __shfl_xor(p, 2);
            p += __shfl_xor(p, 4); p += __shfl_xor(p, 8);
            if (m == 0) s[rb + wv * 16 + quad * 4 + r] = p;  // full row here
        }
    }
}

// ---- fill body: XCD-bucketed padded-CSR fill, 4 edges/thread --------------
// ei is streamed exactly once per XCD (8 consecutive fb -> 8 XCDs), so NT
// loads keep the 5.2 MB edge stream from evicting pad/cur lines from L2.
__device__ __forceinline__
void fill_body(int fb, int tid, const int* __restrict__ ei,
               int* __restrict__ cur_d, int* __restrict__ cur_s,
               unsigned short* __restrict__ pad_src,
               unsigned short* __restrict__ pad_dst)
{
    int bkt = fb & (NBKT - 1);             // == blockIdx&7 (XCD round-robin)
    int q = (fb >> 3) * 256 + tid;
    if (q >= NQ) return;
    int e0 = q * 4;
    i4 sv, dv;
    if (e0 < NE) {                          // quads never straddle NE (NE%4==0)
        sv = __builtin_nontemporal_load((const i4*)(ei + e0));
        dv = __builtin_nontemporal_load((const i4*)(ei + NE + e0));
    } else {
        int b = e0 - NE;
        sv = (i4){b, b + 1, b + 2, b + 3};
        dv = sv;
    }
#pragma unroll
    for (int u = 0; u < 4; ++u) {
        int srcE = sv[u], dstE = dv[u];
        if ((unsigned)dstE / BKT_DIV == (unsigned)bkt) {
            int p = atomicAdd(cur_d + dstE, 1);
            if (p < CAP) pad_src[dstE * CAP + p] = (unsigned short)srcE;
        }
        if ((unsigned)srcE / BKT_DIV == (unsigned)bkt) {
            int p = atomicAdd(cur_s + srcE, 1);
            if (p < CAP) pad_dst[srcE * CAP + p] = (unsigned short)dstE;
        }
    }
}

// ---- fused gemm1 + fill, group-interleaved for co-residency ---------------
// Groups of 72 blocks: 8 gemm + 64 fill; bases all ≡0 mod 8 so fb&7 ==
// blockIdx&7 (XCD bucket affinity survives). Zero LDS + __launch_bounds__
// (256,6): fill blocks now run at up to 24 waves/CU (was 12, LDS-capped).
__global__ __launch_bounds__(256, 6)
void fill_gemm1(const float* __restrict__ x, const _Float16* __restrict__ Wt1,
                const float* __restrict__ b1, const float* __restrict__ att1,
                unsigned char* __restrict__ out8, float* __restrict__ s1,
                const int* __restrict__ ei, int* __restrict__ cur_d,
                int* __restrict__ cur_s, unsigned short* __restrict__ pad_src,
                unsigned short* __restrict__ pad_dst)
{
    int grp = blockIdx.x / GRP, o = blockIdx.x % GRP;
    if (grp < NGRP && o < 8) {
        int g = grp * 8 + o;
        if (g < NGEMMB)
            gemm_direct<true, true>(x, Wt1, b1, att1, out8, s1, g * 64,
                                    threadIdx.x);
        return;
    }
    int fb = (grp < NGRP) ? grp * 64 + (o - 8)
                          : NGRP * 64 + (blockIdx.x - NGRP * GRP);
    if (fb < NFILLB)
        fill_body(fb, threadIdx.x, ei, cur_d, cur_s, pad_src, pad_dst);
}

// ---- standalone gemm (layers 2,3): stage fp16 input + W, run MFMA ---------
template<bool RELU, bool BIAS, bool ATTN>
__global__ __launch_bounds__(256)
void gemm_k(const __half* __restrict__ in, const _Float16* __restrict__ Wt,
            const float* __restrict__ bias, const float* __restrict__ att,
            unsigned char* __restrict__ out8, float* __restrict__ s)
{
    __shared__ __attribute__((aligned(16))) _Float16 xs[64][136];
    __shared__ __attribute__((aligned(16))) _Float16 wt[128][136];
    const int tid = threadIdx.x;
    const int rb = blockIdx.x * 64;
#pragma unroll
    for (int i = 0; i < 4; ++i) {
        int f = tid + i * 256;            // 0..1023 half8 chunks
        int r = f >> 4, c8 = f & 15;
        float4 raw = *(const float4*)(in + (size_t)(rb + r) * CH + c8 * 8);
        if (RELU) {
            __half2* h2 = (__half2*)&raw;
#pragma unroll
            for (int u = 0; u < 4; ++u) {
                float2 fv = __half22float2(h2[u]);
                h2[u] = __floats2half2_rn(fmaxf(fv.x, 0.f), fmaxf(fv.y, 0.f));
            }
        }
        *(float4*)&xs[r][c8 * 8] = raw;
    }
    stage_w(wt, Wt, tid);
    __syncthreads();
    mfma_body<BIAS, ATTN>(xs, wt, bias, att, out8, s, rb, tid);
}

// ------- per-src-node softmax denom (no max-sub; |t|<~20 safe in fp32) -----
__global__ __launch_bounds__(256)
void softmax_stats(const int* __restrict__ cur_s,
                   const unsigned short* __restrict__ pad_dst,
                   const float* __restrict__ s, float* __restrict__ ssum)
{
    int node = (blockIdx.x * 256 + threadIdx.x) >> 6;
    int lane = threadIdx.x & 63;
    if (node >= NN) return;
    int deg = min(cur_s[node], CAP);
    float si = s[node];
    float sum = 0.f;
    if (lane < deg) {
        int d = pad_dst[node * CAP + lane];
        float t = si + s[d];
        t = t > 0.f ? t : 0.2f * t;
        sum = expf(t);
    }
#pragma unroll
    for (int o = 32; o; o >>= 1) sum += __shfl_xor(sum, o);
    if (lane == 0) ssum[node] = sum;
}

// ------- gather core: quad-edge scheme (one node per wave, max TLP) --------
// 4 quarters of 16 lanes; quarter q handles edges base+4u+q. Each lane reads
// uint2 = 8 fp8 (channels 8cl..8cl+7); combine via shfl_xor(16)+shfl_xor(32).
// Lanes >= deg: src=0,w=0 -> weight-0 row-0 reads.
__device__ __forceinline__
void gather_core(int node, int lane, int deg, int src, float w,
                 const unsigned char* __restrict__ h8p, __half* __restrict__ out16)
{
    int qtr = lane >> 4, cl = lane & 15;
    float a[8] = {};
    for (int base = 0; base < deg; base += 8) {
        uint2 v[2]; float wj[2];
#pragma unroll
        for (int u = 0; u < 2; ++u) {
            int e = base + 4 * u + qtr;           // e <= deg+7 <= 55 < 64
            int sj = __shfl(src, e);
            wj[u]  = __shfl(w, e);
            v[u] = ((const uint2*)(h8p + (size_t)sj * CH))[cl];
        }
#pragma unroll
        for (int u = 0; u < 2; ++u) {
            float2 p0 = fp8x2_to_f32((unsigned short)(v[u].x & 0xffff));
            float2 p1 = fp8x2_to_f32((unsigned short)(v[u].x >> 16));
            float2 p2 = fp8x2_to_f32((unsigned short)(v[u].y & 0xffff));
            float2 p3 = fp8x2_to_f32((unsigned short)(v[u].y >> 16));
            a[0] += p0.x * wj[u]; a[1] += p0.y * wj[u];
            a[2] += p1.x * wj[u]; a[3] += p1.y * wj[u];
            a[4] += p2.x * wj[u]; a[5] += p2.y * wj[u];
            a[6] += p3.x * wj[u]; a[7] += p3.y * wj[u];
        }
    }
#pragma unroll
    for (int k = 0; k < 8; ++k) {
        a[k] += __shfl_xor(a[k], 16);
        a[k] += __shfl_xor(a[k], 32);
    }
    if (qtr == 0) {
        float4 st;
        ((__half2*)&st)[0] = __floats2half2_rn(a[0], a[1]);
        ((__half2*)&st)[1] = __floats2half2_rn(a[2], a[3]);
        ((__half2*)&st)[2] = __floats2half2_rn(a[4], a[5]);
        ((__half2*)&st)[3] = __floats2half2_rn(a[6], a[7]);
        ((float4*)(out16 + (size_t)node * CH))[cl] = st;
    }
}

// ------- GT aggregation ----------------------------------------------------
__global__ __launch_bounds__(256)
void gt_gather(const int* __restrict__ cur_d,
               const unsigned short* __restrict__ pad_src,
               const unsigned char* __restrict__ h8p, const float* __restrict__ s,
               const float* __restrict__ ssum, __half* __restrict__ out16)
{
    int node = (blockIdx.x * 256 + threadIdx.x) >> 6;
    int lane = threadIdx.x & 63;
    if (node >= NN) return;
    int deg = min(cur_d[node], CAP);
    float sd = s[node];
    int src = 0; float w = 0.f;
    if (lane < deg) {
        src = pad_src[node * CAP + lane];
        float t = sd + s[src];
        t = t > 0.f ? t : 0.2f * t;
        w = expf(t) / ssum[src];
    }
    gather_core(node, lane, deg, src, w, h8p, out16);
}

// ------- GCN aggregation, inline dinv --------------------------------------
__global__ __launch_bounds__(256)
void gcn_gather(const int* __restrict__ cur_d,
                const unsigned short* __restrict__ pad_src,
                const unsigned char* __restrict__ h8p, __half* __restrict__ out16)
{
    int node = (blockIdx.x * 256 + threadIdx.x) >> 6;
    int lane = threadIdx.x & 63;
    if (node >= NN) return;
    int dn = cur_d[node];
    int deg = min(dn, CAP);
    float nu = rsqrtf((float)max(dn, 1));
    int src = 0; float w = 0.f;
    if (lane < deg) {
        src = pad_src[node * CAP + lane];
        w = rsqrtf((float)max(cur_d[src], 1)) * nu;
    }
    gather_core(node, lane, deg, src, w, h8p, out16);
}

// ---- pooling: 8-deep batched loads; boundary branch is block-uniform ------
__global__ __launch_bounds__(128)
void pool_part(const __half* __restrict__ h16, const int* __restrict__ batch,
               float* __restrict__ pooled)
{
    int ch = threadIdx.x;
    int start = blockIdx.x * 80;
    float acc = 0.f;
    int curg = batch[start];
    for (int base = start; base < start + 80; base += 8) {
        float vals[8]; int gs[8];
#pragma unroll
        for (int u = 0; u < 8; ++u)
            vals[u] = __half2float(h16[(size_t)(base + u) * CH + ch]);
#pragma unroll
        for (int u = 0; u < 8; ++u) gs[u] = batch[base + u];
#pragma unroll
        for (int u = 0; u < 8; ++u) {
            if (gs[u] != curg) {
                atomicAdd(pooled + (size_t)curg * CH + ch, acc);
                acc = 0.f; curg = gs[u];
            }
            acc += vals[u];
        }
    }
    atomicAdd(pooled + (size_t)curg * CH + ch, acc);
}

// ---- head: logits = (psum/cnt + bg) @ Wfc + bfc; log_softmax --------------
__global__ __launch_bounds__(256)
void head_kernel(const float* __restrict__ psum, const int* __restrict__ gstart,
                 const float* __restrict__ bg, const float* __restrict__ Wfc,
                 const float* __restrict__ bfc, float* __restrict__ out)
{
    __shared__ float lg[NG][OC];
    int tid = threadIdx.x;
#pragma unroll
    for (int i = 0; i < 4; ++i) {
        int f = tid + i * 256;        // 0..1023
        int g = f >> 4, o = f & 15;
        float cnt = fmaxf((float)(gstart[g + 1] - gstart[g]), 1.0f);
        float inv = 1.0f / cnt;
        float acc = bfc[o];
        for (int c = 0; c < CH; ++c)
            acc += (psum[g * CH + c] * inv + bg[c]) * Wfc[c * OC + o];
        lg[g][o] = acc;
    }
    __syncthreads();
    if (tid < NG) {
        float m = -1e30f;
#pragma unroll
        for (int o = 0; o < OC; ++o) m = fmaxf(m, lg[tid][o]);
        float sum = 0.f;
#pragma unroll
        for (int o = 0; o < OC; ++o) sum += expf(lg[tid][o] - m);
        float lse = m + logf(sum);
#pragma unroll
        for (int o = 0; o < OC; ++o) out[tid * OC + o] = lg[tid][o] - lse;
    }
}

extern "C" void kernel_launch(void* const* d_in, const int* in_sizes, int n_in,
                              void* d_out, int out_size, void* d_ws, size_t ws_size,
                              hipStream_t stream)
{
    const float* x     = (const float*)d_in[0];
    const int*   ei    = (const int*)d_in[1];
    const int*   batch = (const int*)d_in[2];
    const float* W1    = (const float*)d_in[3];
    const float* b1    = (const float*)d_in[4];
    const float* att1  = (const float*)d_in[5];
    const float* W2    = (const float*)d_in[6];
    const float* b2    = (const float*)d_in[7];
    const float* att2  = (const float*)d_in[8];
    const float* Wg    = (const float*)d_in[9];
    const float* bg    = (const float*)d_in[10];
    const float* Wfc   = (const float*)d_in[11];
    const float* bfc   = (const float*)d_in[12];
    float* out = (float*)d_out;

    const size_t NNCH = (size_t)NN * CH;
    __half* B16 = (__half*)d_ws;                       // [NN*CH] gather output
    unsigned char* A8 = (unsigned char*)(B16 + NNCH);  // [NN*CH] gemm output (fp8)
    _Float16* Wt1 = (_Float16*)(A8 + NNCH);            // [CH*CH]
    _Float16* Wt2 = Wt1 + CH * CH;
    _Float16* Wtg = Wt2 + CH * CH;
    int*   cur_d  = (int*)(Wtg + CH * CH);             // [NN]
    int*   cur_s  = cur_d + NN;                        // [NN]
    float* s1     = (float*)(cur_s + NN);              // [NN]
    float* s2     = s1 + NN;                           // [NN]
    float* pooled = s2 + NN;                           // [NG*CH]
    float* ssum   = pooled + NG * CH;                  // [NN]
    int*   gstart = (int*)(ssum + NN);                 // [NG+1]
    unsigned short* pad_src = (unsigned short*)(gstart + NG + 1);  // [NN*CAP]
    unsigned short* pad_dst = pad_src + (size_t)NN * CAP;          // [NN*CAP]

    const int WB = NN / 4;                 // 10000 (wave-per-node grids)

    prep<<<157, 256, 0, stream>>>(batch, gstart, cur_d, cur_s, pooled,
                                  W1, W2, Wg, Wt1, Wt2, Wtg);

    // ---- GT layer 1: gemm1 co-resident with CSR fill ----------------------
    fill_gemm1<<<NBLK1, 256, 0, stream>>>(
        x, Wt1, b1, att1, A8, s1, ei, cur_d, cur_s, pad_src, pad_dst);
    softmax_stats<<<WB, 256, 0, stream>>>(cur_s, pad_dst, s1, ssum);
    gt_gather<<<WB, 256, 0, stream>>>(cur_d, pad_src, A8, s1, ssum, B16);

    // ---- GT layer 2 (relu folded into gemm input read) --------------------
    gemm_k<true, true, true><<<NGEMMB, 256, 0, stream>>>(
        B16, Wt2, b2, att2, A8, s2);
    softmax_stats<<<WB, 256, 0, stream>>>(cur_s, pad_dst, s2, ssum);
    gt_gather<<<WB, 256, 0, stream>>>(cur_d, pad_src, A8, s2, ssum, B16);

    // ---- GCN layer: fp8 activations, inline dinv --------------------------
    gemm_k<true, false, false><<<NGEMMB, 256, 0, stream>>>(
        B16, Wtg, nullptr, nullptr, A8, nullptr);
    gcn_gather<<<WB, 256, 0, stream>>>(cur_d, pad_src, A8, B16);

    // ---- pool + head ------------------------------------------------------
    pool_part<<<500, 128, 0, stream>>>(B16, batch, pooled);
    head_kernel<<<1, 256, 0, stream>>>(pooled, gstart, bg, Wfc, bfc, out);
}

// Round 2
// 276.167 us; speedup vs baseline: 1.0254x; 1.0254x over previous
//
#include <hip/hip_runtime.h>
#include <hip/hip_fp16.h>
#include <hip/hip_fp8.h>
#include <math.h>

#define NN 40000      // nodes
#define NE 640000     // raw edges
#define ET 680000     // edges + self loops
#define CH 128
#define OC 16
#define NG 64
#define NQ (ET/4)     // 170000 edge quads
#define CAP 48        // padded-CSR capacity per node (deg ~ Poisson(17))
#define NBKT 8        // XCD buckets for pad_fill
#define BKT_DIV 5000  // nodes per bucket
#define NFILLB 5320   // 665 chunks * 8 buckets
#define NGEMMB 625    // 64-row tiles (full 128 cols internal)
#define NGRP 79
#define GRP 72
#define NBLK1 (NGRP*GRP + (NFILLB - NGRP*64))   // 5952

typedef _Float16 h8 __attribute__((ext_vector_type(8)));
typedef float    f4 __attribute__((ext_vector_type(4)));
typedef int      i4 __attribute__((ext_vector_type(4)));

__device__ __forceinline__ float2 fp8x2_to_f32(unsigned short v) {
    __hip_fp8_e4m3 a, b;
    a.__x = (__hip_fp8_storage_t)(v & 0xff);
    b.__x = (__hip_fp8_storage_t)(v >> 8);
    return make_float2((float)a, (float)b);
}
__device__ __forceinline__ unsigned char f32_to_fp8(float f) {
    __hip_fp8_e4m3 t(f);
    return (unsigned char)t.__x;
}

// ---- prep: zero scratch + graph bounds + W->fp16 transposed ---------------
__global__ __launch_bounds__(256)
void prep(const int* __restrict__ batch, int* __restrict__ gstart,
          int* __restrict__ cur_d, int* __restrict__ cur_s,
          float* __restrict__ pooled,
          const float* __restrict__ W1, const float* __restrict__ W2,
          const float* __restrict__ Wg, _Float16* __restrict__ Wt1,
          _Float16* __restrict__ Wt2, _Float16* __restrict__ Wtg)
{
    int i = blockIdx.x * 256 + threadIdx.x;
    if (i < NN) {
        cur_d[i] = 0; cur_s[i] = 0;
        int b = batch[i];
        if (i == 0) { for (int g = 0; g <= b; ++g) gstart[g] = 0; }
        else { int pb = batch[i - 1]; for (int g = pb + 1; g <= b; ++g) gstart[g] = i; }
        if (i == NN - 1) { for (int g = b + 1; g <= NG; ++g) gstart[g] = NN; }
    }
    if (i < NG * CH) pooled[i] = 0.f;
    if (i < CH * CH) {
        int k = i >> 7, n = i & 127;          // coalesced read W[k][n]
        Wt1[n * CH + k] = (_Float16)W1[i];
        Wt2[n * CH + k] = (_Float16)W2[i];
        Wtg[n * CH + k] = (_Float16)Wg[i];
    }
}

// ---- stage Wt (global, [n][k] row-major) into LDS wt[128][136] ------------
__device__ __forceinline__
void stage_w(_Float16 (*wt)[136], const _Float16* __restrict__ Wt, int tid)
{
#pragma unroll
    for (int i = 0; i < 8; ++i) {
        int f = tid + i * 256;            // 0..2047 half8 chunks
        int n = f >> 4, c8 = f & 15;
        *(float4*)&wt[n][c8 * 8] = *(const float4*)(Wt + (size_t)n * CH + c8 * 8);
    }
}

// ---- MFMA body: 64 rows x 128 cols, K=128; xs and wt staged in LDS --------
// A-frag A[m][k=quad*8+j]; C/D col=lane&15, row=quad*4+reg (verified R6).
// b128 LDS reads process 16 lanes/phase -> (m,quad) mapping is 2-way/phase,
// conflict-free. Full row per block -> s[row] is a plain store (no atomic).
template<bool BIAS, bool ATTN>
__device__ __forceinline__
void mfma_body(_Float16 (*xs)[136], _Float16 (*wt)[136],
               const float* __restrict__ bias, const float* __restrict__ att,
               unsigned char* __restrict__ out8, float* __restrict__ s,
               int rb, int tid)
{
    const int wv = tid >> 6, lane = tid & 63;
    const int m = lane & 15, quad = lane >> 4;
    f4 acc[8] = {};
#pragma unroll
    for (int ks = 0; ks < 4; ++ks) {
        h8 a = *(const h8*)&xs[wv * 16 + m][ks * 32 + quad * 8];
#pragma unroll
        for (int t = 0; t < 8; ++t) {
            h8 b = *(const h8*)&wt[t * 16 + m][ks * 32 + quad * 8];
            acc[t] = __builtin_amdgcn_mfma_f32_16x16x32_f16(a, b, acc[t], 0, 0, 0);
        }
    }
    float pr[4] = {0.f, 0.f, 0.f, 0.f};
#pragma unroll
    for (int t = 0; t < 8; ++t) {
        int col = t * 16 + m;
        float bv = BIAS ? bias[col] : 0.f;
        float av = ATTN ? att[col] : 0.f;
#pragma unroll
        for (int r = 0; r < 4; ++r) {
            float o = acc[t][r] + bv;
            int row = rb + wv * 16 + quad * 4 + r;
            out8[(size_t)row * CH + col] = f32_to_fp8(o);
            if (ATTN) pr[r] += o * av;
        }
    }
    if (ATTN) {
#pragma unroll
        for (int r = 0; r < 4; ++r) {
            float p = pr[r];
            p += __shfl_xor(p, 1); p += __shfl_xor(p, 2);
            p += __shfl_xor(p, 4); p += __shfl_xor(p, 8);
            if (m == 0) s[rb + wv * 16 + quad * 4 + r] = p;  // full row here
        }
    }
}

// ---- gemm1 body: A direct from fp32 x (NT load + in-reg cvt, read-once), --
// B from LDS-staged wt (the round-0 fast path). xs eliminated -> LDS
// 52224->34816 B -> 4 blocks/CU co-residency for the fill blocks.
// A loads are issued before the barrier so they overlap wt staging.
template<bool BIAS, bool ATTN>
__device__ __forceinline__
void gemm_wlds(const float* __restrict__ x, _Float16 (*wt)[136],
               const float* __restrict__ bias, const float* __restrict__ att,
               unsigned char* __restrict__ out8, float* __restrict__ s,
               int rb, int tid)
{
    const int wv = tid >> 6, lane = tid & 63;
    const int m = lane & 15, quad = lane >> 4;
    const int arow = rb + wv * 16 + m;
    const float* xp = x + (size_t)arow * CH + quad * 8;
    h8 af[4];
#pragma unroll
    for (int ks = 0; ks < 4; ++ks) {
        f4 v0 = __builtin_nontemporal_load((const f4*)(xp + ks * 32));
        f4 v1 = __builtin_nontemporal_load((const f4*)(xp + ks * 32) + 1);
        h8 a;
        a[0] = (_Float16)v0[0]; a[1] = (_Float16)v0[1];
        a[2] = (_Float16)v0[2]; a[3] = (_Float16)v0[3];
        a[4] = (_Float16)v1[0]; a[5] = (_Float16)v1[1];
        a[6] = (_Float16)v1[2]; a[7] = (_Float16)v1[3];
        af[ks] = a;
    }
    __syncthreads();                       // wt staged (A loads in flight ok)
    f4 acc[8] = {};
#pragma unroll
    for (int ks = 0; ks < 4; ++ks) {
#pragma unroll
        for (int t = 0; t < 8; ++t) {
            h8 b = *(const h8*)&wt[t * 16 + m][ks * 32 + quad * 8];
            acc[t] = __builtin_amdgcn_mfma_f32_16x16x32_f16(af[ks], b, acc[t], 0, 0, 0);
        }
    }
    float pr[4] = {0.f, 0.f, 0.f, 0.f};
#pragma unroll
    for (int t = 0; t < 8; ++t) {
        int col = t * 16 + m;
        float bv = BIAS ? bias[col] : 0.f;
        float av = ATTN ? att[col] : 0.f;
#pragma unroll
        for (int r = 0; r < 4; ++r) {
            float o = acc[t][r] + bv;
            int row = rb + wv * 16 + quad * 4 + r;
            out8[(size_t)row * CH + col] = f32_to_fp8(o);
            if (ATTN) pr[r] += o * av;
        }
    }
    if (ATTN) {
#pragma unroll
        for (int r = 0; r < 4; ++r) {
            float p = pr[r];
            p += __shfl_xor(p, 1); p += __shfl_xor(p, 2);
            p += __shfl_xor(p, 4); p += __shfl_xor(p, 8);
            if (m == 0) s[rb + wv * 16 + quad * 4 + r] = p;  // full row here
        }
    }
}

// ---- fill body: XCD-bucketed padded-CSR fill, 4 edges/thread --------------
// ei is streamed (NT) so the 5.2 MB edge stream doesn't evict pad/cur lines.
__device__ __forceinline__
void fill_body(int fb, int tid, const int* __restrict__ ei,
               int* __restrict__ cur_d, int* __restrict__ cur_s,
               unsigned short* __restrict__ pad_src,
               unsigned short* __restrict__ pad_dst)
{
    int bkt = fb & (NBKT - 1);             // == blockIdx&7 (XCD round-robin)
    int q = (fb >> 3) * 256 + tid;
    if (q >= NQ) return;
    int e0 = q * 4;
    i4 sv, dv;
    if (e0 < NE) {                          // quads never straddle NE (NE%4==0)
        sv = __builtin_nontemporal_load((const i4*)(ei + e0));
        dv = __builtin_nontemporal_load((const i4*)(ei + NE + e0));
    } else {
        int b = e0 - NE;
        sv = (i4){b, b + 1, b + 2, b + 3};
        dv = sv;
    }
#pragma unroll
    for (int u = 0; u < 4; ++u) {
        int srcE = sv[u], dstE = dv[u];
        if ((unsigned)dstE / BKT_DIV == (unsigned)bkt) {
            int p = atomicAdd(cur_d + dstE, 1);
            if (p < CAP) pad_src[dstE * CAP + p] = (unsigned short)srcE;
        }
        if ((unsigned)srcE / BKT_DIV == (unsigned)bkt) {
            int p = atomicAdd(cur_s + srcE, 1);
            if (p < CAP) pad_dst[srcE * CAP + p] = (unsigned short)dstE;
        }
    }
}

// ---- fused gemm1 + fill, group-interleaved for co-residency ---------------
// Groups of 72 blocks: 8 gemm + 64 fill; bases all ≡0 mod 8 so fb&7 ==
// blockIdx&7 (XCD bucket affinity survives). wt-only LDS (34.8 KB) ->
// 4 blocks/CU (was 2 at 52 KB); launch_bounds(256,4) caps VGPR at 128.
__global__ __launch_bounds__(256, 4)
void fill_gemm1(const float* __restrict__ x, const _Float16* __restrict__ Wt1,
                const float* __restrict__ b1, const float* __restrict__ att1,
                unsigned char* __restrict__ out8, float* __restrict__ s1,
                const int* __restrict__ ei, int* __restrict__ cur_d,
                int* __restrict__ cur_s, unsigned short* __restrict__ pad_src,
                unsigned short* __restrict__ pad_dst)
{
    __shared__ __attribute__((aligned(16))) _Float16 wt[128][136];
    int grp = blockIdx.x / GRP, o = blockIdx.x % GRP;
    if (grp < NGRP && o < 8) {
        int g = grp * 8 + o;
        if (g < NGEMMB) {
            stage_w(wt, Wt1, threadIdx.x);
            gemm_wlds<true, true>(x, wt, b1, att1, out8, s1, g * 64,
                                  threadIdx.x);
        }
        return;
    }
    int fb = (grp < NGRP) ? grp * 64 + (o - 8)
                          : NGRP * 64 + (blockIdx.x - NGRP * GRP);
    if (fb < NFILLB)
        fill_body(fb, threadIdx.x, ei, cur_d, cur_s, pad_src, pad_dst);
}

// ---- standalone gemm (layers 2,3): stage fp16 input + W, run MFMA ---------
template<bool RELU, bool BIAS, bool ATTN>
__global__ __launch_bounds__(256)
void gemm_k(const __half* __restrict__ in, const _Float16* __restrict__ Wt,
            const float* __restrict__ bias, const float* __restrict__ att,
            unsigned char* __restrict__ out8, float* __restrict__ s)
{
    __shared__ __attribute__((aligned(16))) _Float16 xs[64][136];
    __shared__ __attribute__((aligned(16))) _Float16 wt[128][136];
    const int tid = threadIdx.x;
    const int rb = blockIdx.x * 64;
#pragma unroll
    for (int i = 0; i < 4; ++i) {
        int f = tid + i * 256;            // 0..1023 half8 chunks
        int r = f >> 4, c8 = f & 15;
        float4 raw = *(const float4*)(in + (size_t)(rb + r) * CH + c8 * 8);
        if (RELU) {
            __half2* h2 = (__half2*)&raw;
#pragma unroll
            for (int u = 0; u < 4; ++u) {
                float2 fv = __half22float2(h2[u]);
                h2[u] = __floats2half2_rn(fmaxf(fv.x, 0.f), fmaxf(fv.y, 0.f));
            }
        }
        *(float4*)&xs[r][c8 * 8] = raw;
    }
    stage_w(wt, Wt, tid);
    __syncthreads();
    mfma_body<BIAS, ATTN>(xs, wt, bias, att, out8, s, rb, tid);
}

// ------- per-src-node softmax denom (no max-sub; |t|<~20 safe in fp32) -----
__global__ __launch_bounds__(256)
void softmax_stats(const int* __restrict__ cur_s,
                   const unsigned short* __restrict__ pad_dst,
                   const float* __restrict__ s, float* __restrict__ ssum)
{
    int node = (blockIdx.x * 256 + threadIdx.x) >> 6;
    int lane = threadIdx.x & 63;
    if (node >= NN) return;
    int deg = min(cur_s[node], CAP);
    float si = s[node];
    float sum = 0.f;
    if (lane < deg) {
        int d = pad_dst[node * CAP + lane];
        float t = si + s[d];
        t = t > 0.f ? t : 0.2f * t;
        sum = expf(t);
    }
#pragma unroll
    for (int o = 32; o; o >>= 1) sum += __shfl_xor(sum, o);
    if (lane == 0) ssum[node] = sum;
}

// ------- gather core: quad-edge scheme (one node per wave, max TLP) --------
// 4 quarters of 16 lanes; quarter q handles edges base+4u+q. Each lane reads
// uint2 = 8 fp8 (channels 8cl..8cl+7); combine via shfl_xor(16)+shfl_xor(32).
// Lanes >= deg: src=0,w=0 -> weight-0 row-0 reads.
__device__ __forceinline__
void gather_core(int node, int lane, int deg, int src, float w,
                 const unsigned char* __restrict__ h8p, __half* __restrict__ out16)
{
    int qtr = lane >> 4, cl = lane & 15;
    float a[8] = {};
    for (int base = 0; base < deg; base += 8) {
        uint2 v[2]; float wj[2];
#pragma unroll
        for (int u = 0; u < 2; ++u) {
            int e = base + 4 * u + qtr;           // e <= deg+7 <= 55 < 64
            int sj = __shfl(src, e);
            wj[u]  = __shfl(w, e);
            v[u] = ((const uint2*)(h8p + (size_t)sj * CH))[cl];
        }
#pragma unroll
        for (int u = 0; u < 2; ++u) {
            float2 p0 = fp8x2_to_f32((unsigned short)(v[u].x & 0xffff));
            float2 p1 = fp8x2_to_f32((unsigned short)(v[u].x >> 16));
            float2 p2 = fp8x2_to_f32((unsigned short)(v[u].y & 0xffff));
            float2 p3 = fp8x2_to_f32((unsigned short)(v[u].y >> 16));
            a[0] += p0.x * wj[u]; a[1] += p0.y * wj[u];
            a[2] += p1.x * wj[u]; a[3] += p1.y * wj[u];
            a[4] += p2.x * wj[u]; a[5] += p2.y * wj[u];
            a[6] += p3.x * wj[u]; a[7] += p3.y * wj[u];
        }
    }
#pragma unroll
    for (int k = 0; k < 8; ++k) {
        a[k] += __shfl_xor(a[k], 16);
        a[k] += __shfl_xor(a[k], 32);
    }
    if (qtr == 0) {
        float4 st;
        ((__half2*)&st)[0] = __floats2half2_rn(a[0], a[1]);
        ((__half2*)&st)[1] = __floats2half2_rn(a[2], a[3]);
        ((__half2*)&st)[2] = __floats2half2_rn(a[4], a[5]);
        ((__half2*)&st)[3] = __floats2half2_rn(a[6], a[7]);
        ((float4*)(out16 + (size_t)node * CH))[cl] = st;
    }
}

// ------- GT aggregation ----------------------------------------------------
__global__ __launch_bounds__(256)
void gt_gather(const int* __restrict__ cur_d,
               const unsigned short* __restrict__ pad_src,
               const unsigned char* __restrict__ h8p, const float* __restrict__ s,
               const float* __restrict__ ssum, __half* __restrict__ out16)
{
    int node = (blockIdx.x * 256 + threadIdx.x) >> 6;
    int lane = threadIdx.x & 63;
    if (node >= NN) return;
    int deg = min(cur_d[node], CAP);
    float sd = s[node];
    int src = 0; float w = 0.f;
    if (lane < deg) {
        src = pad_src[node * CAP + lane];
        float t = sd + s[src];
        t = t > 0.f ? t : 0.2f * t;
        w = expf(t) / ssum[src];
    }
    gather_core(node, lane, deg, src, w, h8p, out16);
}

// ------- GCN aggregation, inline dinv --------------------------------------
__global__ __launch_bounds__(256)
void gcn_gather(const int* __restrict__ cur_d,
                const unsigned short* __restrict__ pad_src,
                const unsigned char* __restrict__ h8p, __half* __restrict__ out16)
{
    int node = (blockIdx.x * 256 + threadIdx.x) >> 6;
    int lane = threadIdx.x & 63;
    if (node >= NN) return;
    int dn = cur_d[node];
    int deg = min(dn, CAP);
    float nu = rsqrtf((float)max(dn, 1));
    int src = 0; float w = 0.f;
    if (lane < deg) {
        src = pad_src[node * CAP + lane];
        w = rsqrtf((float)max(cur_d[src], 1)) * nu;
    }
    gather_core(node, lane, deg, src, w, h8p, out16);
}

// ---- pooling: 8-deep batched loads; boundary branch is block-uniform ------
__global__ __launch_bounds__(128)
void pool_part(const __half* __restrict__ h16, const int* __restrict__ batch,
               float* __restrict__ pooled)
{
    int ch = threadIdx.x;
    int start = blockIdx.x * 80;
    float acc = 0.f;
    int curg = batch[start];
    for (int base = start; base < start + 80; base += 8) {
        float vals[8]; int gs[8];
#pragma unroll
        for (int u = 0; u < 8; ++u)
            vals[u] = __half2float(h16[(size_t)(base + u) * CH + ch]);
#pragma unroll
        for (int u = 0; u < 8; ++u) gs[u] = batch[base + u];
#pragma unroll
        for (int u = 0; u < 8; ++u) {
            if (gs[u] != curg) {
                atomicAdd(pooled + (size_t)curg * CH + ch, acc);
                acc = 0.f; curg = gs[u];
            }
            acc += vals[u];
        }
    }
    atomicAdd(pooled + (size_t)curg * CH + ch, acc);
}

// ---- head: logits = (psum/cnt + bg) @ Wfc + bfc; log_softmax --------------
__global__ __launch_bounds__(256)
void head_kernel(const float* __restrict__ psum, const int* __restrict__ gstart,
                 const float* __restrict__ bg, const float* __restrict__ Wfc,
                 const float* __restrict__ bfc, float* __restrict__ out)
{
    __shared__ float lg[NG][OC];
    int tid = threadIdx.x;
#pragma unroll
    for (int i = 0; i < 4; ++i) {
        int f = tid + i * 256;        // 0..1023
        int g = f >> 4, o = f & 15;
        float cnt = fmaxf((float)(gstart[g + 1] - gstart[g]), 1.0f);
        float inv = 1.0f / cnt;
        float acc = bfc[o];
        for (int c = 0; c < CH; ++c)
            acc += (psum[g * CH + c] * inv + bg[c]) * Wfc[c * OC + o];
        lg[g][o] = acc;
    }
    __syncthreads();
    if (tid < NG) {
        float m = -1e30f;
#pragma unroll
        for (int o = 0; o < OC; ++o) m = fmaxf(m, lg[tid][o]);
        float sum = 0.f;
#pragma unroll
        for (int o = 0; o < OC; ++o) sum += expf(lg[tid][o] - m);
        float lse = m + logf(sum);
#pragma unroll
        for (int o = 0; o < OC; ++o) out[tid * OC + o] = lg[tid][o] - lse;
    }
}

extern "C" void kernel_launch(void* const* d_in, const int* in_sizes, int n_in,
                              void* d_out, int out_size, void* d_ws, size_t ws_size,
                              hipStream_t stream)
{
    const float* x     = (const float*)d_in[0];
    const int*   ei    = (const int*)d_in[1];
    const int*   batch = (const int*)d_in[2];
    const float* W1    = (const float*)d_in[3];
    const float* b1    = (const float*)d_in[4];
    const float* att1  = (const float*)d_in[5];
    const float* W2    = (const float*)d_in[6];
    const float* b2    = (const float*)d_in[7];
    const float* att2  = (const float*)d_in[8];
    const float* Wg    = (const float*)d_in[9];
    const float* bg    = (const float*)d_in[10];
    const float* Wfc   = (const float*)d_in[11];
    const float* bfc   = (const float*)d_in[12];
    float* out = (float*)d_out;

    const size_t NNCH = (size_t)NN * CH;
    __half* B16 = (__half*)d_ws;                       // [NN*CH] gather output
    unsigned char* A8 = (unsigned char*)(B16 + NNCH);  // [NN*CH] gemm output (fp8)
    _Float16* Wt1 = (_Float16*)(A8 + NNCH);            // [CH*CH]
    _Float16* Wt2 = Wt1 + CH * CH;
    _Float16* Wtg = Wt2 + CH * CH;
    int*   cur_d  = (int*)(Wtg + CH * CH);             // [NN]
    int*   cur_s  = cur_d + NN;                        // [NN]
    float* s1     = (float*)(cur_s + NN);              // [NN]
    float* s2     = s1 + NN;                           // [NN]
    float* pooled = s2 + NN;                           // [NG*CH]
    float* ssum   = pooled + NG * CH;                  // [NN]
    int*   gstart = (int*)(ssum + NN);                 // [NG+1]
    unsigned short* pad_src = (unsigned short*)(gstart + NG + 1);  // [NN*CAP]
    unsigned short* pad_dst = pad_src + (size_t)NN * CAP;          // [NN*CAP]

    const int WB = NN / 4;                 // 10000 (wave-per-node grids)

    prep<<<157, 256, 0, stream>>>(batch, gstart, cur_d, cur_s, pooled,
                                  W1, W2, Wg, Wt1, Wt2, Wtg);

    // ---- GT layer 1: gemm1 co-resident with CSR fill ----------------------
    fill_gemm1<<<NBLK1, 256, 0, stream>>>(
        x, Wt1, b1, att1, A8, s1, ei, cur_d, cur_s, pad_src, pad_dst);
    softmax_stats<<<WB, 256, 0, stream>>>(cur_s, pad_dst, s1, ssum);
    gt_gather<<<WB, 256, 0, stream>>>(cur_d, pad_src, A8, s1, ssum, B16);

    // ---- GT layer 2 (relu folded into gemm input read) --------------------
    gemm_k<true, true, true><<<NGEMMB, 256, 0, stream>>>(
        B16, Wt2, b2, att2, A8, s2);
    softmax_stats<<<WB, 256, 0, stream>>>(cur_s, pad_dst, s2, ssum);
    gt_gather<<<WB, 256, 0, stream>>>(cur_d, pad_src, A8, s2, ssum, B16);

    // ---- GCN layer: fp8 activations, inline dinv --------------------------
    gemm_k<true, false, false><<<NGEMMB, 256, 0, stream>>>(
        B16, Wtg, nullptr, nullptr, A8, nullptr);
    gcn_gather<<<WB, 256, 0, stream>>>(cur_d, pad_src, A8, B16);

    // ---- pool + head ------------------------------------------------------
    pool_part<<<500, 128, 0, stream>>>(B16, batch, pooled);
    head_kernel<<<1, 256, 0, stream>>>(pooled, gstart, bg, Wfc, bfc, out);
}